// Round 1
// baseline (475.441 us; speedup 1.0000x reference)
//
#include <hip/hip_runtime.h>
#include <stdint.h>

typedef unsigned short u16;
typedef __attribute__((ext_vector_type(8))) short bf16x8;
typedef __attribute__((ext_vector_type(4))) float f32x4;

#define DEV static __device__ __forceinline__

// problem dims
#define BB    2
#define CC    64
#define DDD   8
#define HHH   32
#define WWW   32
#define DHW   8192
#define MTOT  16384
#define GG    8
#define KTOT  1728
#define NOFF  1296
#define NOFFP 1408
#define COFF  648

// d_out element offsets (out, off1, off2 concatenated)
#define OFF1_ELEM (BB*CC*DHW)                 // 1048576
#define OFF2_ELEM (OFF1_ELEM + BB*COFF*DHW)   // 11665408

// ws byte offsets (all 256-aligned)
#define XCL_OFF   0ull         // bf16 [16384][64] channels-last x
#define YCL_OFF   2097152ull   // bf16 [16384][64] channels-last relu(bn1)
#define WOFF_OFF  4194304ull   // bf16 [1408][1728] off weights (k = tap*64+cin)
#define W1_OFF    9060352ull   // bf16 [64][1728]
#define W2_OFF    9281536ull
#define C1_OFF    9502720ull   // f32 [16384][64] deform1 raw out (channels-last)
#define C2_OFF    13697024ull
#define ST1_OFF   17891328ull  // f32 scale[64], shift[64]
#define ST2_OFF   17891840ull
#define ZPG_OFF   17892352ull  // 256B zeros (OOB source for global_load_lds)
#define ADEF_OFF  17892608ull  // bf16 [8192][1728] per-batch deform im2col

DEV float bf2f(u16 u){ union { uint32_t i; float f; } v; v.i = ((uint32_t)u) << 16; return v.f; }
DEV u16 f2bf(float f){ union { float f; uint32_t i; } v; v.f = f;
  uint32_t r = v.i + 0x7fffu + ((v.i >> 16) & 1u); return (u16)(r >> 16); }

DEV void gld16(const void* g, void* l){
  __builtin_amdgcn_global_load_lds((const __attribute__((address_space(1))) void*)g,
                                   (__attribute__((address_space(3))) void*)l, 16, 0, 0);
}

// ---------------- prep ----------------
__global__ void k_zero(uint32_t* z){ z[threadIdx.x] = 0u; }

__global__ void k_prep_xcl(const float* __restrict__ x, u16* __restrict__ xcl){
  int idx = blockIdx.x * 256 + threadIdx.x;          // over B*C*DHW = 2^20
  if (idx >= BB*CC*DHW) return;
  int p = idx & (DHW - 1);
  int c = (idx >> 13) & 63;
  int b = idx >> 19;
  xcl[(size_t)(b * DHW + p) * CC + c] = f2bf(x[idx]);
}

__global__ void k_prep_woff(const float* __restrict__ wa, const float* __restrict__ wb,
                            u16* __restrict__ wo){
  int idx = blockIdx.x * 256 + threadIdx.x;          // over 1408*1728
  if (idx >= NOFFP * KTOT) return;
  int k = idx % KTOT, n = idx / KTOT;
  int tap = k >> 6, cin = k & 63;
  float v = 0.f;
  if (n < NOFF) {
    const float* w = (n < COFF) ? wa : wb;
    int nn = (n < COFF) ? n : n - COFF;
    v = w[(size_t)nn * KTOT + cin * 27 + tap];
  }
  wo[idx] = f2bf(v);
}

__global__ void k_prep_w(const float* __restrict__ w, u16* __restrict__ wb){
  int idx = blockIdx.x * 256 + threadIdx.x;          // over 64*1728
  if (idx >= CC * KTOT) return;
  int k = idx % KTOT, n = idx / KTOT;
  int tap = k >> 6, cin = k & 63;
  wb[idx] = f2bf(w[(size_t)n * KTOT + cin * 27 + tap]);
}

// ---------------- offset conv GEMM (implicit im2col) ----------------
// C[m][n]: m = b*8192+p (16384), n = off channel (1296, padded 1408), K = 1728
// A[m][tap*64+cin] = xcl[b][p+shift(tap)][cin] or 0 (padding)
__global__ __launch_bounds__(256) void k_gemm_off(
    const u16* __restrict__ xcl, const u16* __restrict__ woff,
    const float* __restrict__ boff1, const float* __restrict__ boff2,
    float* __restrict__ dout, const u16* __restrict__ zpg)
{
  __shared__ u16 Al[128 * 64];
  __shared__ u16 Bl[128 * 64];
  const int tid = threadIdx.x;
  const int wv = tid >> 6, lane = tid & 63;
  const int m0 = blockIdx.x * 128;
  const int n0 = blockIdx.y * 128;
  const int lr = lane >> 3, lc = lane & 7;
  const int b  = m0 >> 13;
  const int p0 = m0 & (DHW - 1);
  // per-lane source rows for the 4 A-staging instructions of this wave
  int ad[4], ah[4], aw[4];
  #pragma unroll
  for (int i = 0; i < 4; ++i) {
    int p = p0 + wv * 32 + i * 8 + lr;
    ad[i] = p >> 10; ah[i] = (p >> 5) & 31; aw[i] = p & 31;
  }
  const size_t xb = (size_t)b * DHW * CC;

  f32x4 acc[4][4] = {};
  const int wm = wv >> 1, wn = wv & 1;
  const int r16 = lane & 15, q = lane >> 4;

  for (int t = 0; t < 27; ++t) {
    int kd = t / 9 - 1, kh = (t / 3) % 3 - 1, kw = t % 3 - 1;
    #pragma unroll
    for (int i = 0; i < 4; ++i) {
      int d2 = ad[i] + kd, h2 = ah[i] + kh, w2 = aw[i] + kw;
      bool ok = ((unsigned)d2 < DDD) & ((unsigned)h2 < HHH) & ((unsigned)w2 < WWW);
      const u16* src = ok ? (xcl + xb + (size_t)((d2 << 10) + (h2 << 5) + w2) * CC + lc * 8)
                          : zpg;
      gld16(src, &Al[(wv * 32 + i * 8) * 64]);
    }
    #pragma unroll
    for (int i = 0; i < 4; ++i) {
      int r = wv * 32 + i * 8 + lr;
      const u16* src = woff + (size_t)(n0 + r) * KTOT + t * 64 + lc * 8;
      gld16(src, &Bl[(wv * 32 + i * 8) * 64]);
    }
    __syncthreads();
    #pragma unroll
    for (int kk = 0; kk < 2; ++kk) {
      bf16x8 af[4], bfr[4];
      #pragma unroll
      for (int i = 0; i < 4; ++i)
        af[i] = *(const bf16x8*)&Al[(wm * 64 + i * 16 + r16) * 64 + kk * 32 + q * 8];
      #pragma unroll
      for (int j = 0; j < 4; ++j)
        bfr[j] = *(const bf16x8*)&Bl[(wn * 64 + j * 16 + r16) * 64 + kk * 32 + q * 8];
      #pragma unroll
      for (int i = 0; i < 4; ++i)
        #pragma unroll
        for (int j = 0; j < 4; ++j)
          acc[i][j] = __builtin_amdgcn_mfma_f32_16x16x32_bf16(af[i], bfr[j], acc[i][j], 0, 0, 0);
    }
    __syncthreads();
  }

  // store: D row = m (lane>>4)*4+reg, col = n (lane&15); scatter to NCDHW off regions
  float biasj[4]; int ncj[4];
  #pragma unroll
  for (int j = 0; j < 4; ++j) {
    int nc = n0 + wn * 64 + j * 16 + r16;
    ncj[j] = nc;
    biasj[j] = (nc < NOFF) ? ((nc < COFF) ? boff1[nc] : boff2[nc - COFF]) : 0.f;
  }
  #pragma unroll
  for (int i = 0; i < 4; ++i) {
    int mrow = m0 + wm * 64 + i * 16 + q * 4;
    int bb = mrow >> 13, p = mrow & (DHW - 1);
    #pragma unroll
    for (int j = 0; j < 4; ++j) {
      int nc = ncj[j];
      if (nc < NOFF) {
        int ch = (nc < COFF) ? nc : nc - COFF;
        size_t base = (nc < COFF) ? (size_t)OFF1_ELEM : (size_t)OFF2_ELEM;
        f32x4 v = acc[i][j] + biasj[j];
        *(f32x4*)(dout + base + ((size_t)(bb * COFF + ch)) * DHW + p) = v;
      }
    }
  }
}

// ---------------- deformable sampling (builds bf16 im2col A for one batch) ----------------
__global__ void k_sample(const u16* __restrict__ src, const float* __restrict__ offs,
                         u16* __restrict__ adef, int b)
{
  int p = blockIdx.x * 256 + threadIdx.x;  // 0..8191
  int t = blockIdx.y;                      // tap 0..26
  int g = blockIdx.z;                      // group 0..7
  int d = p >> 10, h = (p >> 5) & 31, w = p & 31;
  int kd = t / 9 - 1, kh = (t / 3) % 3 - 1, kw = t % 3 - 1;
  size_t ob = ((size_t)b * COFF + (size_t)(g * 81 + t * 3)) * DHW + p;
  float pd = (float)(d + kd) + offs[ob];
  float ph = (float)(h + kh) + offs[ob + DHW];
  float pw = (float)(w + kw) + offs[ob + 2 * DHW];
  float fd0 = floorf(pd), fh0 = floorf(ph), fw0 = floorf(pw);
  float fd = pd - fd0, fh = ph - fh0, fw = pw - fw0;
  int d0 = (int)fd0, h0 = (int)fh0, w0 = (int)fw0;
  const u16* sb = src + (size_t)b * DHW * CC + g * 8;
  float acc[8] = {0.f,0.f,0.f,0.f,0.f,0.f,0.f,0.f};
  #pragma unroll
  for (int dd = 0; dd < 2; ++dd) {
    float wd = dd ? fd : 1.f - fd;
    int di = d0 + dd;
    #pragma unroll
    for (int hh = 0; hh < 2; ++hh) {
      float wh = hh ? fh : 1.f - fh;
      int hi = h0 + hh;
      #pragma unroll
      for (int ww = 0; ww < 2; ++ww) {
        int wi = w0 + ww;
        if (((unsigned)di < DDD) && ((unsigned)hi < HHH) && ((unsigned)wi < WWW)) {
          float wgt = wd * wh * (ww ? fw : 1.f - fw);
          bf16x8 v = *(const bf16x8*)(sb + (size_t)((di << 10) + (hi << 5) + wi) * CC);
          #pragma unroll
          for (int c = 0; c < 8; ++c) acc[c] += wgt * bf2f((u16)v[c]);
        }
      }
    }
  }
  union { bf16x8 v; u16 u[8]; } o;
  #pragma unroll
  for (int c = 0; c < 8; ++c) o.u[c] = f2bf(acc[c]);
  *(bf16x8*)(adef + (size_t)p * KTOT + t * 64 + g * 8) = o.v;
}

// ---------------- deform conv GEMM: A[8192][1728] x W[64][1728]^T -> C[8192][64] ----------------
__global__ __launch_bounds__(256) void k_gemm_def(
    const u16* __restrict__ A, const u16* __restrict__ wb, float* __restrict__ cdst)
{
  __shared__ u16 Al[64 * 64];
  __shared__ u16 Bl[64 * 64];
  const int tid = threadIdx.x;
  const int wv = tid >> 6, lane = tid & 63;
  const int m0 = blockIdx.x * 64;
  const int lr = lane >> 3, lc = lane & 7;
  f32x4 acc[2][2] = {};
  const int wm = wv >> 1, wn = wv & 1;
  const int r16 = lane & 15, q = lane >> 4;

  for (int t = 0; t < 27; ++t) {
    #pragma unroll
    for (int i = 0; i < 2; ++i) {
      int r = wv * 16 + i * 8 + lr;
      gld16(A + (size_t)(m0 + r) * KTOT + t * 64 + lc * 8, &Al[(wv * 16 + i * 8) * 64]);
    }
    #pragma unroll
    for (int i = 0; i < 2; ++i) {
      int r = wv * 16 + i * 8 + lr;
      gld16(wb + (size_t)r * KTOT + t * 64 + lc * 8, &Bl[(wv * 16 + i * 8) * 64]);
    }
    __syncthreads();
    #pragma unroll
    for (int kk = 0; kk < 2; ++kk) {
      bf16x8 af[2], bfr[2];
      #pragma unroll
      for (int i = 0; i < 2; ++i)
        af[i] = *(const bf16x8*)&Al[(wm * 32 + i * 16 + r16) * 64 + kk * 32 + q * 8];
      #pragma unroll
      for (int j = 0; j < 2; ++j)
        bfr[j] = *(const bf16x8*)&Bl[(wn * 32 + j * 16 + r16) * 64 + kk * 32 + q * 8];
      #pragma unroll
      for (int i = 0; i < 2; ++i)
        #pragma unroll
        for (int j = 0; j < 2; ++j)
          acc[i][j] = __builtin_amdgcn_mfma_f32_16x16x32_bf16(af[i], bfr[j], acc[i][j], 0, 0, 0);
    }
    __syncthreads();
  }
  #pragma unroll
  for (int i = 0; i < 2; ++i) {
    int mr = m0 + wm * 32 + i * 16 + q * 4;
    #pragma unroll
    for (int j = 0; j < 2; ++j) {
      int nc = wn * 32 + j * 16 + r16;
      #pragma unroll
      for (int r = 0; r < 4; ++r)
        cdst[(size_t)(mr + r) * CC + nc] = acc[i][j][r];
    }
  }
}

// ---------------- batchnorm ----------------
__global__ void k_bnstats(const float* __restrict__ c, const float* __restrict__ gamma,
                          const float* __restrict__ beta, float* __restrict__ stats)
{
  int n = blockIdx.x, tid = threadIdx.x;
  float s = 0.f, s2 = 0.f;
  for (int m = tid; m < MTOT; m += 256) {
    float v = c[(size_t)m * CC + n];
    s += v; s2 += v * v;
  }
  #pragma unroll
  for (int o = 32; o > 0; o >>= 1) { s += __shfl_down(s, o, 64); s2 += __shfl_down(s2, o, 64); }
  __shared__ float ls[4], ls2[4];
  int w = tid >> 6;
  if ((tid & 63) == 0) { ls[w] = s; ls2[w] = s2; }
  __syncthreads();
  if (tid == 0) {
    float S = ls[0] + ls[1] + ls[2] + ls[3];
    float S2 = ls2[0] + ls2[1] + ls2[2] + ls2[3];
    float mu = S / (float)MTOT;
    float var = S2 / (float)MTOT - mu * mu;
    float sc = gamma[n] / sqrtf(var + 1e-5f);
    stats[n] = sc;
    stats[64 + n] = beta[n] - mu * sc;
  }
}

__global__ void k_apply1(const float* __restrict__ c1, const float* __restrict__ st,
                         u16* __restrict__ ycl)
{
  int idx = blockIdx.x * 256 + threadIdx.x;  // over 16384*64
  if (idx >= MTOT * CC) return;
  int n = idx & 63;
  float v = st[n] * c1[idx] + st[64 + n];
  ycl[idx] = f2bf(fmaxf(v, 0.f));
}

__global__ void k_apply2(const float* __restrict__ c2, const float* __restrict__ st,
                         const float* __restrict__ x, float* __restrict__ out)
{
  int idx = blockIdx.x * 256 + threadIdx.x;  // NCDHW flat, 2^20
  if (idx >= BB * CC * DHW) return;
  int p = idx & (DHW - 1);
  int n = (idx >> 13) & 63;
  int b = idx >> 19;
  float v = st[n] * c2[(size_t)(b * DHW + p) * CC + n] + st[64 + n] + x[idx];
  out[idx] = fmaxf(v, 0.f);
}

// ---------------- host ----------------
extern "C" void kernel_launch(void* const* d_in, const int* in_sizes, int n_in,
                              void* d_out, int out_size, void* d_ws, size_t ws_size,
                              hipStream_t stream)
{
  (void)in_sizes; (void)n_in; (void)out_size; (void)ws_size;
  const float* x      = (const float*)d_in[0];
  const float* w_off1 = (const float*)d_in[1];
  const float* b_off1 = (const float*)d_in[2];
  const float* w1     = (const float*)d_in[3];
  const float* g1     = (const float*)d_in[4];
  const float* be1    = (const float*)d_in[5];
  const float* w_off2 = (const float*)d_in[6];
  const float* b_off2 = (const float*)d_in[7];
  const float* w2     = (const float*)d_in[8];
  const float* g2     = (const float*)d_in[9];
  const float* be2    = (const float*)d_in[10];

  char* ws = (char*)d_ws;
  u16*   xcl  = (u16*)(ws + XCL_OFF);
  u16*   ycl  = (u16*)(ws + YCL_OFF);
  u16*   woff = (u16*)(ws + WOFF_OFF);
  u16*   w1b  = (u16*)(ws + W1_OFF);
  u16*   w2b  = (u16*)(ws + W2_OFF);
  float* c1   = (float*)(ws + C1_OFF);
  float* c2   = (float*)(ws + C2_OFF);
  float* st1  = (float*)(ws + ST1_OFF);
  float* st2  = (float*)(ws + ST2_OFF);
  u16*   zpg  = (u16*)(ws + ZPG_OFF);
  u16*   adef = (u16*)(ws + ADEF_OFF);
  float* out  = (float*)d_out;

  k_zero<<<1, 64, 0, stream>>>((uint32_t*)zpg);
  k_prep_xcl<<<(BB*CC*DHW) / 256, 256, 0, stream>>>(x, xcl);
  k_prep_woff<<<(NOFFP * KTOT + 255) / 256, 256, 0, stream>>>(w_off1, w_off2, woff);
  k_prep_w<<<(CC * KTOT + 255) / 256, 256, 0, stream>>>(w1, w1b);
  k_prep_w<<<(CC * KTOT + 255) / 256, 256, 0, stream>>>(w2, w2b);

  k_gemm_off<<<dim3(MTOT / 128, NOFFP / 128), 256, 0, stream>>>(
      xcl, woff, b_off1, b_off2, out, zpg);

  for (int b = 0; b < 2; ++b) {
    k_sample<<<dim3(DHW / 256, 27, GG), 256, 0, stream>>>(xcl, out + OFF1_ELEM, adef, b);
    k_gemm_def<<<DHW / 64, 256, 0, stream>>>(adef, w1b, c1 + (size_t)b * DHW * CC);
  }
  k_bnstats<<<CC, 256, 0, stream>>>(c1, g1, be1, st1);
  k_apply1<<<(MTOT * CC) / 256, 256, 0, stream>>>(c1, st1, ycl);

  for (int b = 0; b < 2; ++b) {
    k_sample<<<dim3(DHW / 256, 27, GG), 256, 0, stream>>>(ycl, out + OFF2_ELEM, adef, b);
    k_gemm_def<<<DHW / 64, 256, 0, stream>>>(adef, w2b, c2 + (size_t)b * DHW * CC);
  }
  k_bnstats<<<CC, 256, 0, stream>>>(c2, g2, be2, st2);
  k_apply2<<<(BB*CC*DHW) / 256, 256, 0, stream>>>(c2, st2, x, out);
}

// Round 2
// 296.849 us; speedup vs baseline: 1.6016x; 1.6016x over previous
//
#include <hip/hip_runtime.h>
#include <stdint.h>

typedef unsigned short u16;
typedef __attribute__((ext_vector_type(8))) short bf16x8;
typedef __attribute__((ext_vector_type(4))) float f32x4;

#define DEV static __device__ __forceinline__

// problem dims
#define BB    2
#define CC    64
#define DDD   8
#define HHH   32
#define WWW   32
#define DHW   8192
#define MTOT  16384
#define GG    8
#define KTOT  1728
#define NOFF  1296
#define NOFFP 1408
#define COFF  648

// d_out element offsets (out, off1, off2 concatenated)
#define OFF1_ELEM (BB*CC*DHW)                 // 1048576
#define OFF2_ELEM (OFF1_ELEM + BB*COFF*DHW)   // 11665408

// ws byte offsets (all 256-aligned)
#define XCL_OFF   0ull         // bf16 [16384][64] channels-last x
#define YCL_OFF   2097152ull   // bf16 [16384][64] channels-last relu(bn1)
#define WOFF_OFF  4194304ull   // bf16 [1408][1728] off weights (k = tap*64+cin)
#define W1_OFF    9060352ull   // bf16 [64][1728]
#define W2_OFF    9281536ull
#define C1_OFF    9502720ull   // f32 [16384][64] deform1 raw out (channels-last)
#define C2_OFF    13697024ull
#define ST1_OFF   17891328ull  // f32 scale[64], shift[64]
#define ST2_OFF   17891840ull
#define ZPG_OFF   17892352ull  // 256B zeros (OOB source for global_load_lds)
#define PART_OFF  17892608ull  // f32 [256][128] bn partials

DEV float bf2f(u16 u){ union { uint32_t i; float f; } v; v.i = ((uint32_t)u) << 16; return v.f; }
DEV u16 f2bf(float f){ union { float f; uint32_t i; } v; v.f = f;
  uint32_t r = v.i + 0x7fffu + ((v.i >> 16) & 1u); return (u16)(r >> 16); }

DEV void gld16(const void* g, void* l){
  __builtin_amdgcn_global_load_lds((const __attribute__((address_space(1))) void*)g,
                                   (__attribute__((address_space(3))) void*)l, 16, 0, 0);
}

// ---------------- prep ----------------
__global__ void k_zero(uint32_t* z){ z[threadIdx.x] = 0u; }

__global__ void k_prep_xcl(const float* __restrict__ x, u16* __restrict__ xcl){
  int idx = blockIdx.x * 256 + threadIdx.x;          // over B*C*DHW = 2^20
  if (idx >= BB*CC*DHW) return;
  int p = idx & (DHW - 1);
  int c = (idx >> 13) & 63;
  int b = idx >> 19;
  xcl[(size_t)(b * DHW + p) * CC + c] = f2bf(x[idx]);
}

__global__ void k_prep_woff(const float* __restrict__ wa, const float* __restrict__ wb,
                            u16* __restrict__ wo){
  int idx = blockIdx.x * 256 + threadIdx.x;          // over 1408*1728
  if (idx >= NOFFP * KTOT) return;
  int k = idx % KTOT, n = idx / KTOT;
  int tap = k >> 6, cin = k & 63;
  float v = 0.f;
  if (n < NOFF) {
    const float* w = (n < COFF) ? wa : wb;
    int nn = (n < COFF) ? n : n - COFF;
    v = w[(size_t)nn * KTOT + cin * 27 + tap];
  }
  wo[idx] = f2bf(v);
}

__global__ void k_prep_w(const float* __restrict__ w, u16* __restrict__ wb){
  int idx = blockIdx.x * 256 + threadIdx.x;          // over 64*1728
  if (idx >= CC * KTOT) return;
  int k = idx % KTOT, n = idx / KTOT;
  int tap = k >> 6, cin = k & 63;
  wb[idx] = f2bf(w[(size_t)n * KTOT + cin * 27 + tap]);
}

// ---------------- offset conv GEMM (implicit im2col, XOR-swizzled LDS) ----------------
// C[m][n]: m = b*8192+p (16384), n = off channel (1296, padded 1408), K = 1728
// LDS layout: LDS[row][chunk] = global[row][chunk ^ (row&7)]  (chunk = 16B)
// achieved via linear global_load_lds dest + pre-swizzled per-lane SOURCE (rule 21)
__global__ __launch_bounds__(256) void k_gemm_off(
    const u16* __restrict__ xcl, const u16* __restrict__ woff,
    const float* __restrict__ boff1, const float* __restrict__ boff2,
    float* __restrict__ dout, const u16* __restrict__ zpg)
{
  __shared__ u16 Al[128 * 64];
  __shared__ u16 Bl[128 * 64];
  const int tid = threadIdx.x;
  const int wv = tid >> 6, lane = tid & 63;
  const int m0 = blockIdx.x * 128;
  const int n0 = blockIdx.y * 128;
  const int lr = lane >> 3, lc = lane & 7;
  const int lcs = (lc ^ lr) << 3;      // swizzled source element offset within 128B row
  const int b  = m0 >> 13;
  const int p0 = m0 & (DHW - 1);
  int ad[4], ah[4], aw[4];
  #pragma unroll
  for (int i = 0; i < 4; ++i) {
    int p = p0 + wv * 32 + i * 8 + lr;
    ad[i] = p >> 10; ah[i] = (p >> 5) & 31; aw[i] = p & 31;
  }
  const size_t xb = (size_t)b * DHW * CC;

  f32x4 acc[4][4] = {};
  const int wm = wv >> 1, wn = wv & 1;
  const int r16 = lane & 15, q = lane >> 4;
  const int rs = r16 & 7;

  for (int t = 0; t < 27; ++t) {
    int kd = t / 9 - 1, kh = (t / 3) % 3 - 1, kw = t % 3 - 1;
    #pragma unroll
    for (int i = 0; i < 4; ++i) {
      int d2 = ad[i] + kd, h2 = ah[i] + kh, w2 = aw[i] + kw;
      bool ok = ((unsigned)d2 < DDD) & ((unsigned)h2 < HHH) & ((unsigned)w2 < WWW);
      const u16* src = ok ? (xcl + xb + (size_t)((d2 << 10) + (h2 << 5) + w2) * CC + lcs)
                          : zpg;
      gld16(src, &Al[(wv * 32 + i * 8) * 64]);
    }
    #pragma unroll
    for (int i = 0; i < 4; ++i) {
      int r = wv * 32 + i * 8 + lr;
      const u16* src = woff + (size_t)(n0 + r) * KTOT + t * 64 + lcs;
      gld16(src, &Bl[(wv * 32 + i * 8) * 64]);
    }
    __syncthreads();
    #pragma unroll
    for (int kk = 0; kk < 2; ++kk) {
      const int cs = ((kk * 4 + q) ^ rs) << 3;   // swizzled read chunk
      bf16x8 af[4], bfr[4];
      #pragma unroll
      for (int i = 0; i < 4; ++i)
        af[i] = *(const bf16x8*)&Al[(wm * 64 + i * 16 + r16) * 64 + cs];
      #pragma unroll
      for (int j = 0; j < 4; ++j)
        bfr[j] = *(const bf16x8*)&Bl[(wn * 64 + j * 16 + r16) * 64 + cs];
      #pragma unroll
      for (int i = 0; i < 4; ++i)
        #pragma unroll
        for (int j = 0; j < 4; ++j)
          acc[i][j] = __builtin_amdgcn_mfma_f32_16x16x32_bf16(af[i], bfr[j], acc[i][j], 0, 0, 0);
    }
    __syncthreads();
  }

  float biasj[4]; int ncj[4];
  #pragma unroll
  for (int j = 0; j < 4; ++j) {
    int nc = n0 + wn * 64 + j * 16 + r16;
    ncj[j] = nc;
    biasj[j] = (nc < NOFF) ? ((nc < COFF) ? boff1[nc] : boff2[nc - COFF]) : 0.f;
  }
  #pragma unroll
  for (int i = 0; i < 4; ++i) {
    int mrow = m0 + wm * 64 + i * 16 + q * 4;
    int bb = mrow >> 13, p = mrow & (DHW - 1);
    #pragma unroll
    for (int j = 0; j < 4; ++j) {
      int nc = ncj[j];
      if (nc < NOFF) {
        int ch = (nc < COFF) ? nc : nc - COFF;
        size_t base = (nc < COFF) ? (size_t)OFF1_ELEM : (size_t)OFF2_ELEM;
        f32x4 v = acc[i][j] + biasj[j];
        *(f32x4*)(dout + base + ((size_t)(bb * COFF + ch)) * DHW + p) = v;
      }
    }
  }
}

// ---------------- fused deformable sampling + GEMM ----------------
// Per block: 32 output rows (positions). Per tap: sample A-tile 32x64 into LDS
// (ds_write, XOR-swizzled), stage W-tile 64x64 (global_load_lds, source-swizzled),
// then MFMA. C[16384][64] f32 channels-last.
__global__ __launch_bounds__(256) void k_deform(
    const u16* __restrict__ src, const float* __restrict__ offs,
    const u16* __restrict__ wB, float* __restrict__ cdst)
{
  __shared__ u16 Al[32 * 64];
  __shared__ u16 Bl[64 * 64];
  const int tid = threadIdx.x;
  const int wv = tid >> 6, lane = tid & 63;
  const int mrow0 = blockIdx.x * 32;
  const int b  = mrow0 >> 13;
  const int p0 = mrow0 & (DHW - 1);

  // sampling task: one (p_local, g) per thread
  const int pl = tid & 31;
  const int g  = tid >> 5;
  const int p  = p0 + pl;
  const int d = p >> 10, h = (p >> 5) & 31, w = p & 31;
  const u16* sb = src + (size_t)b * DHW * CC + g * 8;
  const size_t obase = ((size_t)(b * COFF + g * 81)) * DHW + p;
  const int awz = ((g ^ (pl & 7)) << 3);   // swizzled A write chunk offset (elements)

  // B staging source (swizzled chunk)
  const int br_sub = lane >> 3;            // row within 8-row segment
  const int bcs = ((lane & 7) ^ br_sub) << 3;

  f32x4 acc[2] = {};
  const int wm = wv >> 1, wn = wv & 1;
  const int r16 = lane & 15, q = lane >> 4;
  const int rs = r16 & 7;

  for (int t = 0; t < 27; ++t) {
    int kd = t / 9 - 1, kh = (t / 3) % 3 - 1, kw = t % 3 - 1;
    // ---- stage B tile (rows = 64 out-channels, cols = 64 k of this tap) ----
    #pragma unroll
    for (int k = 0; k < 2; ++k) {
      int seg = k * 4 + wv;
      int r = seg * 8 + br_sub;
      gld16(wB + (size_t)r * KTOT + t * 64 + bcs, &Bl[seg * 512]);
    }
    // ---- sample A tile ----
    {
      size_t ob = obase + (size_t)(t * 3) * DHW;
      float pd = (float)(d + kd) + offs[ob];
      float ph = (float)(h + kh) + offs[ob + DHW];
      float pw = (float)(w + kw) + offs[ob + 2 * DHW];
      float fd0 = floorf(pd), fh0 = floorf(ph), fw0 = floorf(pw);
      float fd = pd - fd0, fh = ph - fh0, fw = pw - fw0;
      int d0 = (int)fd0, h0 = (int)fh0, w0 = (int)fw0;
      float a8[8] = {0.f,0.f,0.f,0.f,0.f,0.f,0.f,0.f};
      #pragma unroll
      for (int dd = 0; dd < 2; ++dd) {
        float wd = dd ? fd : 1.f - fd;
        int di = d0 + dd;
        #pragma unroll
        for (int hh = 0; hh < 2; ++hh) {
          float wh = hh ? fh : 1.f - fh;
          int hi = h0 + hh;
          #pragma unroll
          for (int ww = 0; ww < 2; ++ww) {
            int wi = w0 + ww;
            if (((unsigned)di < DDD) && ((unsigned)hi < HHH) && ((unsigned)wi < WWW)) {
              float wgt = wd * wh * (ww ? fw : 1.f - fw);
              bf16x8 v = *(const bf16x8*)(sb + (size_t)((di << 10) + (hi << 5) + wi) * CC);
              #pragma unroll
              for (int c = 0; c < 8; ++c) a8[c] += wgt * bf2f((u16)v[c]);
            }
          }
        }
      }
      union { bf16x8 v; u16 u[8]; } o;
      #pragma unroll
      for (int c = 0; c < 8; ++c) o.u[c] = f2bf(a8[c]);
      *(bf16x8*)&Al[pl * 64 + awz] = o.v;
    }
    __syncthreads();
    // ---- MFMA: per-wave 16x32 tile ----
    #pragma unroll
    for (int kk = 0; kk < 2; ++kk) {
      const int cs = ((kk * 4 + q) ^ rs) << 3;
      bf16x8 af = *(const bf16x8*)&Al[(wm * 16 + r16) * 64 + cs];
      #pragma unroll
      for (int j = 0; j < 2; ++j) {
        bf16x8 bf_ = *(const bf16x8*)&Bl[(wn * 32 + j * 16 + r16) * 64 + cs];
        acc[j] = __builtin_amdgcn_mfma_f32_16x16x32_bf16(af, bf_, acc[j], 0, 0, 0);
      }
    }
    __syncthreads();
  }

  #pragma unroll
  for (int j = 0; j < 2; ++j) {
    int nc = wn * 32 + j * 16 + r16;
    int mr = mrow0 + wm * 16 + q * 4;
    #pragma unroll
    for (int r = 0; r < 4; ++r)
      cdst[(size_t)(mr + r) * CC + nc] = acc[j][r];
  }
}

// ---------------- batchnorm (2-stage, coalesced) ----------------
__global__ void k_bnpart(const float* __restrict__ c, float* __restrict__ part)
{
  int k = blockIdx.x, tid = threadIdx.x;
  int ch = tid & 63, sub = tid >> 6;
  float s = 0.f, s2 = 0.f;
  for (int mm = sub; mm < 64; mm += 4) {
    float v = c[(size_t)(k * 64 + mm) * CC + ch];
    s += v; s2 += v * v;
  }
  __shared__ float sh[4][128];
  sh[sub][ch] = s; sh[sub][64 + ch] = s2;
  __syncthreads();
  if (tid < 128)
    part[(size_t)k * 128 + tid] = sh[0][tid] + sh[1][tid] + sh[2][tid] + sh[3][tid];
}

__global__ void k_bnfin(const float* __restrict__ part, const float* __restrict__ gamma,
                        const float* __restrict__ beta, float* __restrict__ stats)
{
  int n = threadIdx.x;  // 0..63
  float S = 0.f, S2 = 0.f;
  for (int k = 0; k < 256; ++k) {
    S  += part[(size_t)k * 128 + n];
    S2 += part[(size_t)k * 128 + 64 + n];
  }
  float mu = S / (float)MTOT;
  float var = S2 / (float)MTOT - mu * mu;
  float sc = gamma[n] / sqrtf(var + 1e-5f);
  stats[n] = sc;
  stats[64 + n] = beta[n] - mu * sc;
}

__global__ void k_apply1(const float* __restrict__ c1, const float* __restrict__ st,
                         u16* __restrict__ ycl)
{
  int idx = blockIdx.x * 256 + threadIdx.x;  // over 16384*64
  if (idx >= MTOT * CC) return;
  int n = idx & 63;
  float v = st[n] * c1[idx] + st[64 + n];
  ycl[idx] = f2bf(fmaxf(v, 0.f));
}

__global__ void k_apply2(const float* __restrict__ c2, const float* __restrict__ st,
                         const float* __restrict__ x, float* __restrict__ out)
{
  int idx = blockIdx.x * 256 + threadIdx.x;  // NCDHW flat, 2^20
  if (idx >= BB * CC * DHW) return;
  int p = idx & (DHW - 1);
  int n = (idx >> 13) & 63;
  int b = idx >> 19;
  float v = st[n] * c2[(size_t)(b * DHW + p) * CC + n] + st[64 + n] + x[idx];
  out[idx] = fmaxf(v, 0.f);
}

// ---------------- host ----------------
extern "C" void kernel_launch(void* const* d_in, const int* in_sizes, int n_in,
                              void* d_out, int out_size, void* d_ws, size_t ws_size,
                              hipStream_t stream)
{
  (void)in_sizes; (void)n_in; (void)out_size; (void)ws_size;
  const float* x      = (const float*)d_in[0];
  const float* w_off1 = (const float*)d_in[1];
  const float* b_off1 = (const float*)d_in[2];
  const float* w1     = (const float*)d_in[3];
  const float* g1     = (const float*)d_in[4];
  const float* be1    = (const float*)d_in[5];
  const float* w_off2 = (const float*)d_in[6];
  const float* b_off2 = (const float*)d_in[7];
  const float* w2     = (const float*)d_in[8];
  const float* g2     = (const float*)d_in[9];
  const float* be2    = (const float*)d_in[10];

  char* ws = (char*)d_ws;
  u16*   xcl  = (u16*)(ws + XCL_OFF);
  u16*   ycl  = (u16*)(ws + YCL_OFF);
  u16*   woff = (u16*)(ws + WOFF_OFF);
  u16*   w1b  = (u16*)(ws + W1_OFF);
  u16*   w2b  = (u16*)(ws + W2_OFF);
  float* c1   = (float*)(ws + C1_OFF);
  float* c2   = (float*)(ws + C2_OFF);
  float* st1  = (float*)(ws + ST1_OFF);
  float* st2  = (float*)(ws + ST2_OFF);
  u16*   zpg  = (u16*)(ws + ZPG_OFF);
  float* part = (float*)(ws + PART_OFF);
  float* out  = (float*)d_out;

  k_zero<<<1, 64, 0, stream>>>((uint32_t*)zpg);
  k_prep_xcl<<<(BB*CC*DHW) / 256, 256, 0, stream>>>(x, xcl);
  k_prep_woff<<<(NOFFP * KTOT + 255) / 256, 256, 0, stream>>>(w_off1, w_off2, woff);
  k_prep_w<<<(CC * KTOT + 255) / 256, 256, 0, stream>>>(w1, w1b);
  k_prep_w<<<(CC * KTOT + 255) / 256, 256, 0, stream>>>(w2, w2b);

  k_gemm_off<<<dim3(MTOT / 128, NOFFP / 128), 256, 0, stream>>>(
      xcl, woff, b_off1, b_off2, out, zpg);

  k_deform<<<MTOT / 32, 256, 0, stream>>>(xcl, out + OFF1_ELEM, w1b, c1);
  k_bnpart<<<256, 256, 0, stream>>>(c1, part);
  k_bnfin<<<1, 64, 0, stream>>>(part, g1, be1, st1);
  k_apply1<<<(MTOT * CC) / 256, 256, 0, stream>>>(c1, st1, ycl);

  k_deform<<<MTOT / 32, 256, 0, stream>>>(ycl, out + OFF2_ELEM, w2b, c2);
  k_bnpart<<<256, 256, 0, stream>>>(c2, part);
  k_bnfin<<<1, 64, 0, stream>>>(part, g2, be2, st2);
  k_apply2<<<(BB*CC*DHW) / 256, 256, 0, stream>>>(c2, st2, x, out);
}

// Round 3
// 278.368 us; speedup vs baseline: 1.7080x; 1.0664x over previous
//
#include <hip/hip_runtime.h>
#include <stdint.h>

typedef unsigned short u16;
typedef __attribute__((ext_vector_type(8))) short bf16x8;
typedef __attribute__((ext_vector_type(4))) float f32x4;

#define DEV static __device__ __forceinline__

// problem dims
#define BB    2
#define CC    64
#define DDD   8
#define HHH   32
#define WWW   32
#define DHW   8192
#define MTOT  16384
#define GG    8
#define KTOT  1728
#define NOFF  1296
#define NOFFP 1408
#define COFF  648

// d_out element offsets (out, off1, off2 concatenated)
#define OFF1_ELEM (BB*CC*DHW)                 // 1048576
#define OFF2_ELEM (OFF1_ELEM + BB*COFF*DHW)   // 11665408

// ws byte offsets (all 256-aligned)
#define XCL_OFF   0ull         // bf16 [16384][64] channels-last x
#define YCL_OFF   2097152ull   // bf16 [16384][64] channels-last relu(bn1)
#define WOFF_OFF  4194304ull   // bf16 [1408][1728] off weights (k = tap*64+cin)
#define W1_OFF    9060352ull   // bf16 [64][1728]
#define W2_OFF    9281536ull
#define C1_OFF    9502720ull   // f32 [16384][64] deform1 raw out (channels-last)
#define C2_OFF    13697024ull
#define ST1_OFF   17891328ull  // f32 scale[64], shift[64]
#define ST2_OFF   17891840ull
#define ZPG_OFF   17892352ull  // 256B zeros (OOB source for global_load_lds)
#define PART_OFF  17892608ull  // f32 [256][128] bn partials

DEV float bf2f(u16 u){ union { uint32_t i; float f; } v; v.i = ((uint32_t)u) << 16; return v.f; }
DEV u16 f2bf(float f){ union { float f; uint32_t i; } v; v.f = f;
  uint32_t r = v.i + 0x7fffu + ((v.i >> 16) & 1u); return (u16)(r >> 16); }

DEV void gld16(const void* g, void* l){
  __builtin_amdgcn_global_load_lds((const __attribute__((address_space(1))) void*)g,
                                   (__attribute__((address_space(3))) void*)l, 16, 0, 0);
}

// ---------------- prep ----------------
__global__ void k_zero(uint32_t* z){ z[threadIdx.x] = 0u; }

__global__ void k_prep_xcl(const float* __restrict__ x, u16* __restrict__ xcl){
  int idx = blockIdx.x * 256 + threadIdx.x;          // over B*C*DHW = 2^20
  if (idx >= BB*CC*DHW) return;
  int p = idx & (DHW - 1);
  int c = (idx >> 13) & 63;
  int b = idx >> 19;
  xcl[(size_t)(b * DHW + p) * CC + c] = f2bf(x[idx]);
}

__global__ void k_prep_woff(const float* __restrict__ wa, const float* __restrict__ wb,
                            u16* __restrict__ wo){
  int idx = blockIdx.x * 256 + threadIdx.x;          // over 1408*1728
  if (idx >= NOFFP * KTOT) return;
  int k = idx % KTOT, n = idx / KTOT;
  int tap = k >> 6, cin = k & 63;
  float v = 0.f;
  if (n < NOFF) {
    const float* w = (n < COFF) ? wa : wb;
    int nn = (n < COFF) ? n : n - COFF;
    v = w[(size_t)nn * KTOT + cin * 27 + tap];
  }
  wo[idx] = f2bf(v);
}

__global__ void k_prep_w(const float* __restrict__ w, u16* __restrict__ wb){
  int idx = blockIdx.x * 256 + threadIdx.x;          // over 64*1728
  if (idx >= CC * KTOT) return;
  int k = idx % KTOT, n = idx / KTOT;
  int tap = k >> 6, cin = k & 63;
  wb[idx] = f2bf(w[(size_t)n * KTOT + cin * 27 + tap]);
}

// ---------------- offset conv GEMM (implicit im2col, XOR-swizzled LDS) ----------------
// BM=256, BN=128, 512 threads (8 waves, each a 64x64 sub-tile).
// LDS layout: LDS[row][chunk] = global[row][chunk ^ (row&7)]  (chunk = 16B)
__global__ __launch_bounds__(512) void k_gemm_off(
    const u16* __restrict__ xcl, const u16* __restrict__ woff,
    const float* __restrict__ boff1, const float* __restrict__ boff2,
    float* __restrict__ dout, const u16* __restrict__ zpg)
{
  __shared__ u16 Al[256 * 64];   // 32KB
  __shared__ u16 Bl[128 * 64];   // 16KB
  const int tid = threadIdx.x;
  const int wv = tid >> 6, lane = tid & 63;
  const int m0 = blockIdx.x * 256;
  const int n0 = blockIdx.y * 128;
  const int lr = lane >> 3, lc = lane & 7;
  const int lcs = (lc ^ lr) << 3;      // swizzled source element offset within 128B row
  const int b  = m0 >> 13;
  const int p0 = m0 & (DHW - 1);
  int ad[4], ah[4], aw[4];
  #pragma unroll
  for (int i = 0; i < 4; ++i) {
    int p = p0 + wv * 32 + i * 8 + lr;
    ad[i] = p >> 10; ah[i] = (p >> 5) & 31; aw[i] = p & 31;
  }
  const size_t xb = (size_t)b * DHW * CC;

  f32x4 acc[4][4] = {};
  const int wm = wv >> 1, wn = wv & 1;   // wm 0..3 (M 64-quads), wn 0..1 (N halves)
  const int r16 = lane & 15, q = lane >> 4;
  const int rs = r16 & 7;

  for (int t = 0; t < 27; ++t) {
    int kd = t / 9 - 1, kh = (t / 3) % 3 - 1, kw = t % 3 - 1;
    #pragma unroll
    for (int i = 0; i < 4; ++i) {
      int d2 = ad[i] + kd, h2 = ah[i] + kh, w2 = aw[i] + kw;
      bool ok = ((unsigned)d2 < DDD) & ((unsigned)h2 < HHH) & ((unsigned)w2 < WWW);
      const u16* src = ok ? (xcl + xb + (size_t)((d2 << 10) + (h2 << 5) + w2) * CC + lcs)
                          : zpg;
      gld16(src, &Al[(wv * 32 + i * 8) * 64]);
    }
    #pragma unroll
    for (int i = 0; i < 2; ++i) {
      int r = wv * 16 + i * 8 + lr;
      const u16* src = woff + (size_t)(n0 + r) * KTOT + t * 64 + lcs;
      gld16(src, &Bl[(wv * 16 + i * 8) * 64]);
    }
    __syncthreads();
    #pragma unroll
    for (int kk = 0; kk < 2; ++kk) {
      const int cs = ((kk * 4 + q) ^ rs) << 3;   // swizzled read chunk
      bf16x8 af[4], bfr[4];
      #pragma unroll
      for (int i = 0; i < 4; ++i)
        af[i] = *(const bf16x8*)&Al[(wm * 64 + i * 16 + r16) * 64 + cs];
      #pragma unroll
      for (int j = 0; j < 4; ++j)
        bfr[j] = *(const bf16x8*)&Bl[(wn * 64 + j * 16 + r16) * 64 + cs];
      #pragma unroll
      for (int i = 0; i < 4; ++i)
        #pragma unroll
        for (int j = 0; j < 4; ++j)
          acc[i][j] = __builtin_amdgcn_mfma_f32_16x16x32_bf16(af[i], bfr[j], acc[i][j], 0, 0, 0);
    }
    __syncthreads();
  }

  float biasj[4]; int ncj[4];
  #pragma unroll
  for (int j = 0; j < 4; ++j) {
    int nc = n0 + wn * 64 + j * 16 + r16;
    ncj[j] = nc;
    biasj[j] = (nc < NOFF) ? ((nc < COFF) ? boff1[nc] : boff2[nc - COFF]) : 0.f;
  }
  #pragma unroll
  for (int i = 0; i < 4; ++i) {
    int mrow = m0 + wm * 64 + i * 16 + q * 4;
    int bb = mrow >> 13, p = mrow & (DHW - 1);
    #pragma unroll
    for (int j = 0; j < 4; ++j) {
      int nc = ncj[j];
      if (nc < NOFF) {
        int ch = (nc < COFF) ? nc : nc - COFF;
        size_t base = (nc < COFF) ? (size_t)OFF1_ELEM : (size_t)OFF2_ELEM;
        f32x4 v = acc[i][j] + biasj[j];
        *(f32x4*)(dout + base + ((size_t)(bb * COFF + ch)) * DHW + p) = v;
      }
    }
  }
}

// ---------------- fused deformable sampling + GEMM ----------------
// 512 threads, 32 output rows/block, 2 taps per barrier-phase (14 phases, tap 27 zero-pad).
// A tile [2][32][64] bf16 (ds_write, XOR-swizzled); B tile [2][64][64]
// (global_load_lds, source-swizzled). C[16384][64] f32 channels-last.
__global__ __launch_bounds__(512) void k_deform(
    const u16* __restrict__ src, const float* __restrict__ offs,
    const u16* __restrict__ wB, float* __restrict__ cdst,
    const u16* __restrict__ zpg)
{
  __shared__ u16 Al[2 * 32 * 64];   // 8KB
  __shared__ u16 Bl[2 * 64 * 64];   // 16KB
  const int tid = threadIdx.x;
  const int wv = tid >> 6, lane = tid & 63;
  const int mrow0 = blockIdx.x * 32;
  const int b  = mrow0 >> 13;
  const int p0 = mrow0 & (DHW - 1);

  // sampling role: one (p_local, g, tap-half) per thread
  const int pl = tid & 31;
  const int g  = (tid >> 5) & 7;
  const int th = tid >> 8;
  const int p  = p0 + pl;
  const int d = p >> 10, h = (p >> 5) & 31, w = p & 31;
  const u16* sb = src + (size_t)b * DHW * CC + g * 8;
  const size_t obase = ((size_t)(b * COFF + g * 81)) * DHW + p;
  u16* awp = &Al[th * 2048 + pl * 64 + ((g ^ (pl & 7)) << 3)];

  // B staging role: 2 gld16/thread (i = tap-half), row=(tid>>3)&63, chunk=tid&7
  const int brow = (tid >> 3) & 63;
  const int bch  = tid & 7;
  const int bcs  = ((bch ^ (brow & 7)) << 3);

  f32x4 acc = {};
  const int wm = wv >> 2, wn = wv & 3;   // wave sub-tile 16M x 16N
  const int r16 = lane & 15, q = lane >> 4;
  const int rs = r16 & 7;

  for (int ph = 0; ph < 14; ++ph) {
    // ---- stage B tiles for taps 2ph, 2ph+1 ----
    #pragma unroll
    for (int i = 0; i < 2; ++i) {
      int tb = 2 * ph + i;
      const u16* s = (tb < 27) ? (wB + (size_t)brow * KTOT + tb * 64 + bcs) : zpg;
      gld16(s, &Bl[(i * 512 + wv * 64) * 8]);
    }
    // ---- sample A tile for tap t = 2ph + th ----
    {
      int t = 2 * ph + th;
      float a8[8] = {0.f,0.f,0.f,0.f,0.f,0.f,0.f,0.f};
      if (t < 27) {
        int kd = t / 9 - 1, kh = (t / 3) % 3 - 1, kw = t % 3 - 1;
        size_t ob = obase + (size_t)(t * 3) * DHW;
        float pd = (float)(d + kd) + offs[ob];
        float phh = (float)(h + kh) + offs[ob + DHW];
        float pw = (float)(w + kw) + offs[ob + 2 * DHW];
        float fd0 = floorf(pd), fh0 = floorf(phh), fw0 = floorf(pw);
        float fd = pd - fd0, fh = phh - fh0, fw = pw - fw0;
        int d0 = (int)fd0, h0 = (int)fh0, w0 = (int)fw0;
        #pragma unroll
        for (int dd = 0; dd < 2; ++dd) {
          float wd = dd ? fd : 1.f - fd;
          int di = d0 + dd;
          #pragma unroll
          for (int hh = 0; hh < 2; ++hh) {
            float wh = hh ? fh : 1.f - fh;
            int hi = h0 + hh;
            #pragma unroll
            for (int ww = 0; ww < 2; ++ww) {
              int wi = w0 + ww;
              if (((unsigned)di < DDD) && ((unsigned)hi < HHH) && ((unsigned)wi < WWW)) {
                float wgt = wd * wh * (ww ? fw : 1.f - fw);
                bf16x8 v = *(const bf16x8*)(sb + (size_t)((di << 10) + (hi << 5) + wi) * CC);
                #pragma unroll
                for (int c = 0; c < 8; ++c) a8[c] += wgt * bf2f((u16)v[c]);
              }
            }
          }
        }
      }
      union { bf16x8 v; u16 u[8]; } o;
      #pragma unroll
      for (int c = 0; c < 8; ++c) o.u[c] = f2bf(a8[c]);
      *(bf16x8*)awp = o.v;
    }
    __syncthreads();
    // ---- MFMA: K=128 (2 taps x 64) ----
    #pragma unroll
    for (int tt = 0; tt < 2; ++tt) {
      #pragma unroll
      for (int kk = 0; kk < 2; ++kk) {
        const int cs = ((kk * 4 + q) ^ rs) << 3;
        bf16x8 af = *(const bf16x8*)&Al[tt * 2048 + (wm * 16 + r16) * 64 + cs];
        bf16x8 bf_ = *(const bf16x8*)&Bl[tt * 4096 + (wn * 16 + r16) * 64 + cs];
        acc = __builtin_amdgcn_mfma_f32_16x16x32_bf16(af, bf_, acc, 0, 0, 0);
      }
    }
    __syncthreads();
  }

  {
    int nc = wn * 16 + r16;
    int mr = mrow0 + wm * 16 + q * 4;
    #pragma unroll
    for (int r = 0; r < 4; ++r)
      cdst[(size_t)(mr + r) * CC + nc] = acc[r];
  }
}

// ---------------- batchnorm (2-stage, coalesced) ----------------
__global__ void k_bnpart(const float* __restrict__ c, float* __restrict__ part)
{
  int k = blockIdx.x, tid = threadIdx.x;
  int ch = tid & 63, sub = tid >> 6;
  float s = 0.f, s2 = 0.f;
  for (int mm = sub; mm < 64; mm += 4) {
    float v = c[(size_t)(k * 64 + mm) * CC + ch];
    s += v; s2 += v * v;
  }
  __shared__ float sh[4][128];
  sh[sub][ch] = s; sh[sub][64 + ch] = s2;
  __syncthreads();
  if (tid < 128)
    part[(size_t)k * 128 + tid] = sh[0][tid] + sh[1][tid] + sh[2][tid] + sh[3][tid];
}

__global__ void k_bnfin(const float* __restrict__ part, const float* __restrict__ gamma,
                        const float* __restrict__ beta, float* __restrict__ stats)
{
  int n = threadIdx.x;  // 0..63
  float S = 0.f, S2 = 0.f;
  for (int k = 0; k < 256; ++k) {
    S  += part[(size_t)k * 128 + n];
    S2 += part[(size_t)k * 128 + 64 + n];
  }
  float mu = S / (float)MTOT;
  float var = S2 / (float)MTOT - mu * mu;
  float sc = gamma[n] / sqrtf(var + 1e-5f);
  stats[n] = sc;
  stats[64 + n] = beta[n] - mu * sc;
}

__global__ void k_apply1(const float* __restrict__ c1, const float* __restrict__ st,
                         u16* __restrict__ ycl)
{
  int idx = blockIdx.x * 256 + threadIdx.x;  // over 16384*64
  if (idx >= MTOT * CC) return;
  int n = idx & 63;
  float v = st[n] * c1[idx] + st[64 + n];
  ycl[idx] = f2bf(fmaxf(v, 0.f));
}

__global__ void k_apply2(const float* __restrict__ c2, const float* __restrict__ st,
                         const float* __restrict__ x, float* __restrict__ out)
{
  int idx = blockIdx.x * 256 + threadIdx.x;  // NCDHW flat, 2^20
  if (idx >= BB * CC * DHW) return;
  int p = idx & (DHW - 1);
  int n = (idx >> 13) & 63;
  int b = idx >> 19;
  float v = st[n] * c2[(size_t)(b * DHW + p) * CC + n] + st[64 + n] + x[idx];
  out[idx] = fmaxf(v, 0.f);
}

// ---------------- host ----------------
extern "C" void kernel_launch(void* const* d_in, const int* in_sizes, int n_in,
                              void* d_out, int out_size, void* d_ws, size_t ws_size,
                              hipStream_t stream)
{
  (void)in_sizes; (void)n_in; (void)out_size; (void)ws_size;
  const float* x      = (const float*)d_in[0];
  const float* w_off1 = (const float*)d_in[1];
  const float* b_off1 = (const float*)d_in[2];
  const float* w1     = (const float*)d_in[3];
  const float* g1     = (const float*)d_in[4];
  const float* be1    = (const float*)d_in[5];
  const float* w_off2 = (const float*)d_in[6];
  const float* b_off2 = (const float*)d_in[7];
  const float* w2     = (const float*)d_in[8];
  const float* g2     = (const float*)d_in[9];
  const float* be2    = (const float*)d_in[10];

  char* ws = (char*)d_ws;
  u16*   xcl  = (u16*)(ws + XCL_OFF);
  u16*   ycl  = (u16*)(ws + YCL_OFF);
  u16*   woff = (u16*)(ws + WOFF_OFF);
  u16*   w1b  = (u16*)(ws + W1_OFF);
  u16*   w2b  = (u16*)(ws + W2_OFF);
  float* c1   = (float*)(ws + C1_OFF);
  float* c2   = (float*)(ws + C2_OFF);
  float* st1  = (float*)(ws + ST1_OFF);
  float* st2  = (float*)(ws + ST2_OFF);
  u16*   zpg  = (u16*)(ws + ZPG_OFF);
  float* part = (float*)(ws + PART_OFF);
  float* out  = (float*)d_out;

  k_zero<<<1, 64, 0, stream>>>((uint32_t*)zpg);
  k_prep_xcl<<<(BB*CC*DHW) / 256, 256, 0, stream>>>(x, xcl);
  k_prep_woff<<<(NOFFP * KTOT + 255) / 256, 256, 0, stream>>>(w_off1, w_off2, woff);
  k_prep_w<<<(CC * KTOT + 255) / 256, 256, 0, stream>>>(w1, w1b);
  k_prep_w<<<(CC * KTOT + 255) / 256, 256, 0, stream>>>(w2, w2b);

  k_gemm_off<<<dim3(MTOT / 256, NOFFP / 128), 512, 0, stream>>>(
      xcl, woff, b_off1, b_off2, out, zpg);

  k_deform<<<MTOT / 32, 512, 0, stream>>>(xcl, out + OFF1_ELEM, w1b, c1, zpg);
  k_bnpart<<<256, 256, 0, stream>>>(c1, part);
  k_bnfin<<<1, 64, 0, stream>>>(part, g1, be1, st1);
  k_apply1<<<(MTOT * CC) / 256, 256, 0, stream>>>(c1, st1, ycl);

  k_deform<<<MTOT / 32, 512, 0, stream>>>(ycl, out + OFF2_ELEM, w2b, c2, zpg);
  k_bnpart<<<256, 256, 0, stream>>>(c2, part);
  k_bnfin<<<1, 64, 0, stream>>>(part, g2, be2, st2);
  k_apply2<<<(BB*CC*DHW) / 256, 256, 0, stream>>>(c2, st2, x, out);
}

// Round 4
// 259.921 us; speedup vs baseline: 1.8292x; 1.0710x over previous
//
#include <hip/hip_runtime.h>
#include <stdint.h>

typedef unsigned short u16;
typedef __attribute__((ext_vector_type(8))) short bf16x8;
typedef __attribute__((ext_vector_type(4))) float f32x4;

#define DEV static __device__ __forceinline__

// problem dims
#define BB    2
#define CC    64
#define DDD   8
#define HHH   32
#define WWW   32
#define DHW   8192
#define MTOT  16384
#define GG    8
#define KTOT  1728
#define NOFF  1296
#define NOFFP 1408
#define COFF  648

// d_out element offsets (out, off1, off2 concatenated)
#define OFF1_ELEM (BB*CC*DHW)                 // 1048576
#define OFF2_ELEM (OFF1_ELEM + BB*COFF*DHW)   // 11665408

// ws byte offsets (all 256-aligned)
#define XCL_OFF   0ull         // bf16 [16384][64] channels-last x
#define YCL_OFF   2097152ull   // bf16 [16384][64] channels-last relu(bn1)
#define WOFF_OFF  4194304ull   // bf16 [1408][1728] off weights (k = tap*64+cin)
#define W1_OFF    9060352ull   // bf16 [64][1728]
#define W2_OFF    9281536ull
#define C1_OFF    9502720ull   // f32 [16384][64] deform1 raw out (channels-last)
#define C2_OFF    13697024ull
#define ST1_OFF   17891328ull  // f32 scale[64], shift[64]
#define ST2_OFF   17891840ull
#define ZPG_OFF   17892352ull  // 256B zeros (OOB source for global_load_lds)
#define PART_OFF  17892608ull  // f32 [256][128] bn partials

DEV float bf2f(u16 u){ union { uint32_t i; float f; } v; v.i = ((uint32_t)u) << 16; return v.f; }
DEV u16 f2bf(float f){ union { float f; uint32_t i; } v; v.f = f;
  uint32_t r = v.i + 0x7fffu + ((v.i >> 16) & 1u); return (u16)(r >> 16); }

DEV void gld16(const void* g, void* l){
  __builtin_amdgcn_global_load_lds((const __attribute__((address_space(1))) void*)g,
                                   (__attribute__((address_space(3))) void*)l, 16, 0, 0);
}

// ---------------- merged prep ----------------
#define PRE0 (BB*CC*DHW)            // xcl
#define PRE1 (PRE0 + NOFFP*KTOT)    // woff
#define PRE2 (PRE1 + CC*KTOT)       // w1b
#define PRE3 (PRE2 + CC*KTOT)       // w2b
#define PRETOT (PRE3 + 128)         // zpg (128 u16)

__global__ void k_prep(const float* __restrict__ x,
                       const float* __restrict__ wo1, const float* __restrict__ wo2,
                       const float* __restrict__ w1, const float* __restrict__ w2,
                       u16* __restrict__ xcl, u16* __restrict__ woff,
                       u16* __restrict__ w1b, u16* __restrict__ w2b,
                       u16* __restrict__ zpg)
{
  int idx = blockIdx.x * 256 + threadIdx.x;
  if (idx < PRE0) {
    int p = idx & (DHW - 1);
    int c = (idx >> 13) & 63;
    int b = idx >> 19;
    xcl[(size_t)(b * DHW + p) * CC + c] = f2bf(x[idx]);
  } else if (idx < PRE1) {
    int j = idx - PRE0;
    int k = j % KTOT, n = j / KTOT;
    int tap = k >> 6, cin = k & 63;
    float v = 0.f;
    if (n < NOFF) {
      const float* w = (n < COFF) ? wo1 : wo2;
      int nn = (n < COFF) ? n : n - COFF;
      v = w[(size_t)nn * KTOT + cin * 27 + tap];
    }
    woff[j] = f2bf(v);
  } else if (idx < PRE2) {
    int j = idx - PRE1;
    int k = j % KTOT, n = j / KTOT;
    int tap = k >> 6, cin = k & 63;
    w1b[j] = f2bf(w1[(size_t)n * KTOT + cin * 27 + tap]);
  } else if (idx < PRE3) {
    int j = idx - PRE2;
    int k = j % KTOT, n = j / KTOT;
    int tap = k >> 6, cin = k & 63;
    w2b[j] = f2bf(w2[(size_t)n * KTOT + cin * 27 + tap]);
  } else if (idx < PRETOT) {
    zpg[idx - PRE3] = 0;
  }
}

// ---------------- offset conv GEMM (implicit im2col, XOR-swizzled LDS) ----------------
// BM=BN=128, 256 threads (R1 shape: 5 blocks/CU). N-trim via wave-uniform jlim.
// LDS layout: LDS[row][chunk] = global[row][chunk ^ (row&7)]  (chunk = 16B)
__global__ __launch_bounds__(256) void k_gemm_off(
    const u16* __restrict__ xcl, const u16* __restrict__ woff,
    const float* __restrict__ boff1, const float* __restrict__ boff2,
    float* __restrict__ dout, const u16* __restrict__ zpg)
{
  __shared__ u16 Al[128 * 64];
  __shared__ u16 Bl[128 * 64];
  const int tid = threadIdx.x;
  const int wv = tid >> 6, lane = tid & 63;
  const int m0 = blockIdx.x * 128;
  const int n0 = blockIdx.y * 128;
  const int lr = lane >> 3, lc = lane & 7;
  const int lcs = (lc ^ lr) << 3;      // swizzled source element offset within 128B row
  const int b  = m0 >> 13;
  const int p0 = m0 & (DHW - 1);
  int ad[4], ah[4], aw[4];
  #pragma unroll
  for (int i = 0; i < 4; ++i) {
    int p = p0 + wv * 32 + i * 8 + lr;
    ad[i] = p >> 10; ah[i] = (p >> 5) & 31; aw[i] = p & 31;
  }
  const size_t xb = (size_t)b * DHW * CC;

  f32x4 acc[4][4] = {};
  const int wm = wv >> 1, wn = wv & 1;
  const int r16 = lane & 15, q = lane >> 4;
  const int rs = r16 & 7;
  // N-trim: number of valid 16-col j-tiles for this wave (wave-uniform)
  const int nbase = n0 + wn * 64;
  const int jlim = (nbase >= NOFF) ? 0 : ((NOFF - nbase >= 64) ? 4 : ((NOFF - nbase + 15) >> 4));

  for (int t = 0; t < 27; ++t) {
    int kd = t / 9 - 1, kh = (t / 3) % 3 - 1, kw = t % 3 - 1;
    #pragma unroll
    for (int i = 0; i < 4; ++i) {
      int d2 = ad[i] + kd, h2 = ah[i] + kh, w2 = aw[i] + kw;
      bool ok = ((unsigned)d2 < DDD) & ((unsigned)h2 < HHH) & ((unsigned)w2 < WWW);
      const u16* src = ok ? (xcl + xb + (size_t)((d2 << 10) + (h2 << 5) + w2) * CC + lcs)
                          : zpg;
      gld16(src, &Al[(wv * 32 + i * 8) * 64]);
    }
    #pragma unroll
    for (int i = 0; i < 4; ++i) {
      int r = wv * 32 + i * 8 + lr;
      const u16* src = woff + (size_t)(n0 + r) * KTOT + t * 64 + lcs;
      gld16(src, &Bl[(wv * 32 + i * 8) * 64]);
    }
    __syncthreads();
    #pragma unroll
    for (int kk = 0; kk < 2; ++kk) {
      const int cs = ((kk * 4 + q) ^ rs) << 3;   // swizzled read chunk
      bf16x8 af[4];
      #pragma unroll
      for (int i = 0; i < 4; ++i)
        af[i] = *(const bf16x8*)&Al[(wm * 64 + i * 16 + r16) * 64 + cs];
      #pragma unroll
      for (int j = 0; j < 4; ++j) {
        if (j < jlim) {
          bf16x8 bfr = *(const bf16x8*)&Bl[(wn * 64 + j * 16 + r16) * 64 + cs];
          #pragma unroll
          for (int i = 0; i < 4; ++i)
            acc[i][j] = __builtin_amdgcn_mfma_f32_16x16x32_bf16(af[i], bfr, acc[i][j], 0, 0, 0);
        }
      }
    }
    __syncthreads();
  }

  float biasj[4]; int ncj[4];
  #pragma unroll
  for (int j = 0; j < 4; ++j) {
    int nc = n0 + wn * 64 + j * 16 + r16;
    ncj[j] = nc;
    biasj[j] = (nc < NOFF) ? ((nc < COFF) ? boff1[nc] : boff2[nc - COFF]) : 0.f;
  }
  #pragma unroll
  for (int i = 0; i < 4; ++i) {
    int mrow = m0 + wm * 64 + i * 16 + q * 4;
    int bb = mrow >> 13, p = mrow & (DHW - 1);
    #pragma unroll
    for (int j = 0; j < 4; ++j) {
      int nc = ncj[j];
      if (nc < NOFF) {
        int ch = (nc < COFF) ? nc : nc - COFF;
        size_t base = (nc < COFF) ? (size_t)OFF1_ELEM : (size_t)OFF2_ELEM;
        f32x4 v = acc[i][j] + biasj[j];
        *(f32x4*)(dout + base + ((size_t)(bb * COFF + ch)) * DHW + p) = v;
      }
    }
  }
}

// ---------------- fused deformable sampling + GEMM ----------------
// 256 threads (4 waves), 16 output rows/block, grid 1024 (4 blocks/CU).
// Wave spans 16 pos x 4 groups -> corner gathers hit ~16 lines/instr (4 lanes/line).
// 2 taps/phase (14 phases, tap 27 zero-padded).
__global__ __launch_bounds__(256) void k_deform(
    const u16* __restrict__ src, const float* __restrict__ offs,
    const u16* __restrict__ wB, float* __restrict__ cdst,
    const u16* __restrict__ zpg)
{
  __shared__ u16 Al[2 * 16 * 64];   // 4KB  [tapHalf][pos][64ch], XOR-swizzled chunks
  __shared__ u16 Bl[2 * 64 * 64];   // 16KB [tapHalf][outch][64k], XOR-swizzled chunks
  const int tid = threadIdx.x;
  const int wv = tid >> 6, lane = tid & 63;
  const int mrow0 = blockIdx.x * 16;
  const int b  = mrow0 >> 13;
  const int p0 = mrow0 & (DHW - 1);

  // sampling role: (pos, group, tap-half)
  const int pl = tid & 15;
  const int g  = (tid >> 4) & 7;
  const int th = tid >> 7;
  const int p  = p0 + pl;
  const int d = p >> 10, h = (p >> 5) & 31, w = p & 31;
  const u16* sb = src + (size_t)b * DHW * CC + g * 8;
  const size_t obase = ((size_t)(b * COFF + g * 81)) * DHW + p;
  u16* awp = &Al[th * 1024 + pl * 64 + ((g ^ (pl & 7)) << 3)];

  // B staging role: 4 gld16/thread covering 2 taps x 64 rows x 8 chunks
  const int lr = lane >> 3, lc = lane & 7;
  const int lcs = (lc ^ lr) << 3;   // row&7 == lr for all staged rows

  f32x4 acc = {};
  const int r16 = lane & 15, q = lane >> 4;
  const int rs = r16 & 7;

  for (int ph = 0; ph < 14; ++ph) {
    // ---- stage B tiles for taps 2ph, 2ph+1 ----
    #pragma unroll
    for (int i = 0; i < 4; ++i) {
      int tb = 2 * ph + (i >> 1);
      int row = (i & 1) * 32 + wv * 8 + lr;
      const u16* s = (tb < 27) ? (wB + (size_t)row * KTOT + tb * 64 + lcs) : zpg;
      gld16(s, &Bl[(i >> 1) * 4096 + (((i & 1) * 32 + wv * 8) * 64)]);
    }
    // ---- sample A for tap t = 2ph + th ----
    {
      int t = 2 * ph + th;
      float a8[8] = {0.f,0.f,0.f,0.f,0.f,0.f,0.f,0.f};
      if (t < 27) {
        int kd = t / 9 - 1, kh = (t / 3) % 3 - 1, kw = t % 3 - 1;
        size_t ob = obase + (size_t)(t * 3) * DHW;
        float pd = (float)(d + kd) + offs[ob];
        float phh = (float)(h + kh) + offs[ob + DHW];
        float pw = (float)(w + kw) + offs[ob + 2 * DHW];
        float fd0 = floorf(pd), fh0 = floorf(phh), fw0 = floorf(pw);
        float fd = pd - fd0, fh = phh - fh0, fw = pw - fw0;
        int d0 = (int)fd0, h0 = (int)fh0, w0 = (int)fw0;
        #pragma unroll
        for (int dd = 0; dd < 2; ++dd) {
          float wd = dd ? fd : 1.f - fd;
          int di = d0 + dd;
          #pragma unroll
          for (int hh = 0; hh < 2; ++hh) {
            float wh = hh ? fh : 1.f - fh;
            int hi = h0 + hh;
            #pragma unroll
            for (int ww = 0; ww < 2; ++ww) {
              int wi = w0 + ww;
              if (((unsigned)di < DDD) && ((unsigned)hi < HHH) && ((unsigned)wi < WWW)) {
                float wgt = wd * wh * (ww ? fw : 1.f - fw);
                bf16x8 v = *(const bf16x8*)(sb + (size_t)((di << 10) + (hi << 5) + wi) * CC);
                #pragma unroll
                for (int c = 0; c < 8; ++c) a8[c] += wgt * bf2f((u16)v[c]);
              }
            }
          }
        }
      }
      union { bf16x8 v; u16 u[8]; } o;
      #pragma unroll
      for (int c = 0; c < 8; ++c) o.u[c] = f2bf(a8[c]);
      *(bf16x8*)awp = o.v;
    }
    __syncthreads();
    // ---- MFMA: K=128 (2 taps x 64); all waves share A rows, wave wv = outch tile ----
    #pragma unroll
    for (int tt = 0; tt < 2; ++tt) {
      #pragma unroll
      for (int kk = 0; kk < 2; ++kk) {
        const int cs = ((kk * 4 + q) ^ rs) << 3;
        bf16x8 af = *(const bf16x8*)&Al[tt * 1024 + r16 * 64 + cs];
        bf16x8 bf_ = *(const bf16x8*)&Bl[tt * 4096 + (wv * 16 + r16) * 64 + cs];
        acc = __builtin_amdgcn_mfma_f32_16x16x32_bf16(af, bf_, acc, 0, 0, 0);
      }
    }
    __syncthreads();
  }

  {
    int nc = wv * 16 + r16;
    int mr = mrow0 + q * 4;
    #pragma unroll
    for (int r = 0; r < 4; ++r)
      cdst[(size_t)(mr + r) * CC + nc] = acc[r];
  }
}

// ---------------- batchnorm (2-stage, coalesced) ----------------
__global__ void k_bnpart(const float* __restrict__ c, float* __restrict__ part)
{
  int k = blockIdx.x, tid = threadIdx.x;
  int ch = tid & 63, sub = tid >> 6;
  float s = 0.f, s2 = 0.f;
  for (int mm = sub; mm < 64; mm += 4) {
    float v = c[(size_t)(k * 64 + mm) * CC + ch];
    s += v; s2 += v * v;
  }
  __shared__ float sh[4][128];
  sh[sub][ch] = s; sh[sub][64 + ch] = s2;
  __syncthreads();
  if (tid < 128)
    part[(size_t)k * 128 + tid] = sh[0][tid] + sh[1][tid] + sh[2][tid] + sh[3][tid];
}

__global__ void k_bnfin(const float* __restrict__ part, const float* __restrict__ gamma,
                        const float* __restrict__ beta, float* __restrict__ stats)
{
  int n = threadIdx.x;  // 0..63
  float S = 0.f, S2 = 0.f;
  for (int k = 0; k < 256; ++k) {
    S  += part[(size_t)k * 128 + n];
    S2 += part[(size_t)k * 128 + 64 + n];
  }
  float mu = S / (float)MTOT;
  float var = S2 / (float)MTOT - mu * mu;
  float sc = gamma[n] / sqrtf(var + 1e-5f);
  stats[n] = sc;
  stats[64 + n] = beta[n] - mu * sc;
}

__global__ void k_apply1(const float* __restrict__ c1, const float* __restrict__ st,
                         u16* __restrict__ ycl)
{
  int idx = blockIdx.x * 256 + threadIdx.x;  // over 16384*64
  if (idx >= MTOT * CC) return;
  int n = idx & 63;
  float v = st[n] * c1[idx] + st[64 + n];
  ycl[idx] = f2bf(fmaxf(v, 0.f));
}

__global__ void k_apply2(const float* __restrict__ c2, const float* __restrict__ st,
                         const float* __restrict__ x, float* __restrict__ out)
{
  int idx = blockIdx.x * 256 + threadIdx.x;  // NCDHW flat, 2^20
  if (idx >= BB * CC * DHW) return;
  int p = idx & (DHW - 1);
  int n = (idx >> 13) & 63;
  int b = idx >> 19;
  float v = st[n] * c2[(size_t)(b * DHW + p) * CC + n] + st[64 + n] + x[idx];
  out[idx] = fmaxf(v, 0.f);
}

// ---------------- host ----------------
extern "C" void kernel_launch(void* const* d_in, const int* in_sizes, int n_in,
                              void* d_out, int out_size, void* d_ws, size_t ws_size,
                              hipStream_t stream)
{
  (void)in_sizes; (void)n_in; (void)out_size; (void)ws_size;
  const float* x      = (const float*)d_in[0];
  const float* w_off1 = (const float*)d_in[1];
  const float* b_off1 = (const float*)d_in[2];
  const float* w1     = (const float*)d_in[3];
  const float* g1     = (const float*)d_in[4];
  const float* be1    = (const float*)d_in[5];
  const float* w_off2 = (const float*)d_in[6];
  const float* b_off2 = (const float*)d_in[7];
  const float* w2     = (const float*)d_in[8];
  const float* g2     = (const float*)d_in[9];
  const float* be2    = (const float*)d_in[10];

  char* ws = (char*)d_ws;
  u16*   xcl  = (u16*)(ws + XCL_OFF);
  u16*   ycl  = (u16*)(ws + YCL_OFF);
  u16*   woff = (u16*)(ws + WOFF_OFF);
  u16*   w1b  = (u16*)(ws + W1_OFF);
  u16*   w2b  = (u16*)(ws + W2_OFF);
  float* c1   = (float*)(ws + C1_OFF);
  float* c2   = (float*)(ws + C2_OFF);
  float* st1  = (float*)(ws + ST1_OFF);
  float* st2  = (float*)(ws + ST2_OFF);
  u16*   zpg  = (u16*)(ws + ZPG_OFF);
  float* part = (float*)(ws + PART_OFF);
  float* out  = (float*)d_out;

  k_prep<<<(PRETOT + 255) / 256, 256, 0, stream>>>(
      x, w_off1, w_off2, w1, w2, xcl, woff, w1b, w2b, zpg);

  k_gemm_off<<<dim3(MTOT / 128, NOFFP / 128), 256, 0, stream>>>(
      xcl, woff, b_off1, b_off2, out, zpg);

  k_deform<<<MTOT / 16, 256, 0, stream>>>(xcl, out + OFF1_ELEM, w1b, c1, zpg);
  k_bnpart<<<256, 256, 0, stream>>>(c1, part);
  k_bnfin<<<1, 64, 0, stream>>>(part, g1, be1, st1);
  k_apply1<<<(MTOT * CC) / 256, 256, 0, stream>>>(c1, st1, ycl);

  k_deform<<<MTOT / 16, 256, 0, stream>>>(ycl, out + OFF2_ELEM, w2b, c2, zpg);
  k_bnpart<<<256, 256, 0, stream>>>(c2, part);
  k_bnfin<<<1, 64, 0, stream>>>(part, g2, be2, st2);
  k_apply2<<<(BB*CC*DHW) / 256, 256, 0, stream>>>(c2, st2, x, out);
}